// Round 8
// baseline (1291.384 us; speedup 1.0000x reference)
//
#include <hip/hip_runtime.h>
#include <math.h>

#define IN_CH 128
#define H1N 8
#define C1N 16
#define C2N 64
#define NEG_SLOPE 0.2f

#define BKT_SHIFT 7                 // 128 nodes per bucket
#define BKT_NODES (1 << BKT_SHIFT)
#define NBLK 128                    // blocks for count/bin passes

typedef unsigned short ushortT;

__device__ __forceinline__ ushortT f2bf(float f) {
    unsigned u = __float_as_uint(f);
    unsigned r = u + 0x7FFFu + ((u >> 16) & 1u);
    return (ushortT)(r >> 16);
}
__device__ __forceinline__ float bf2f(ushortT b) {
    return __uint_as_float(((unsigned)b) << 16);
}
__device__ __forceinline__ float leaky(float x) {
    return (x > 0.f) ? x : NEG_SLOPE * x;
}

// ---------------- CSR-bucket build: deterministic counting sort, no global atomics ----------------

__global__ __launch_bounds__(512) void k_cnt(const int* __restrict__ src,
                                             const int* __restrict__ dst,
                                             int E, int N, int* __restrict__ cnt) {
    __shared__ int hist[512];
    int blk = blockIdx.x, t = threadIdx.x;
    int nb = (N + BKT_NODES - 1) >> BKT_SHIFT;
    if (t < nb) hist[t] = 0;
    __syncthreads();
    int Etot = E + N;
    int chunk = (Etot + gridDim.x - 1) / gridDim.x;
    int lo = blk * chunk;
    int hi = lo + chunk; if (hi > Etot) hi = Etot;
    for (int i = lo + t; i < hi; i += 512) {
        int d = (i < E) ? dst[i] : (i - E);
        atomicAdd(&hist[d >> BKT_SHIFT], 1);
    }
    __syncthreads();
    if (t < nb) cnt[t * NBLK + blk] = hist[t];
}

__global__ __launch_bounds__(NBLK) void k_scanrel(int* __restrict__ cnt,
                                                  int* __restrict__ bucketTotal) {
    __shared__ int sh[NBLK];
    int b = blockIdx.x, t = threadIdx.x;
    sh[t] = cnt[b * NBLK + t];
    __syncthreads();
    for (int off = 1; off < NBLK; off <<= 1) {
        int v = (t >= off) ? sh[t - off] : 0;
        __syncthreads();
        sh[t] += v;
        __syncthreads();
    }
    if (t == NBLK - 1) bucketTotal[b] = sh[t];
    cnt[b * NBLK + t] = (t == 0) ? 0 : sh[t - 1];
}

__global__ __launch_bounds__(512) void k_scanbucket(const int* __restrict__ bucketTotal,
                                                    int nb, int* __restrict__ bBase) {
    __shared__ int sh[512];
    int t = threadIdx.x;
    sh[t] = (t < nb) ? bucketTotal[t] : 0;
    __syncthreads();
    for (int off = 1; off < 512; off <<= 1) {
        int v = (t >= off) ? sh[t - off] : 0;
        __syncthreads();
        sh[t] += v;
        __syncthreads();
    }
    if (t < nb) bBase[t] = (t == 0) ? 0 : sh[t - 1];
    if (t == 511) bBase[nb] = sh[511];
}

__global__ __launch_bounds__(512) void k_bin(const int* __restrict__ src,
                                             const int* __restrict__ dst,
                                             int E, int N,
                                             const int* __restrict__ cnt,
                                             const int* __restrict__ bBase,
                                             unsigned* __restrict__ pair) {
    __shared__ int cur[512];
    int blk = blockIdx.x, t = threadIdx.x;
    int nb = (N + BKT_NODES - 1) >> BKT_SHIFT;
    if (t < nb) cur[t] = bBase[t] + cnt[t * NBLK + blk];
    __syncthreads();
    int Etot = E + N;
    int chunk = (Etot + gridDim.x - 1) / gridDim.x;
    int lo = blk * chunk;
    int hi = lo + chunk; if (hi > Etot) hi = Etot;
    for (int i = lo + t; i < hi; i += 512) {
        int s, d;
        if (i < E) { s = src[i]; d = dst[i]; }
        else       { s = d = i - E; }
        int b = d >> BKT_SHIFT;
        int pos = atomicAdd(&cur[b], 1);
        pair[pos] = ((unsigned)(d & (BKT_NODES - 1)) << 16) | (unsigned)s;
    }
}

// ---------------- GEMM + fused attention coefficients ----------------

template <int KOUT, int HEADS>
__global__ __launch_bounds__(256) void k_gemm_att(const float* __restrict__ A,
                                                  const float* __restrict__ W,
                                                  const float* __restrict__ att_s,
                                                  const float* __restrict__ att_d,
                                                  int N, ushortT* __restrict__ Cbf,
                                                  float* __restrict__ as_,
                                                  float* __restrict__ ad_) {
    constexpr int CG  = KOUT / 4;
    constexpr int TY  = 256 / CG;
    constexpr int RPT = 64 / TY;
    constexpr int RW  = (KOUT / HEADS) / 4;
    static_assert(RW == 4 || RW == 16, "reduce width");
    __shared__ float As[64][16];
    __shared__ float Ws[16][KOUT];
    int t = threadIdx.x;
    int row0 = blockIdx.x * 64;
    int tx = t % CG, ty = t / CG;

    float4 acc[RPT];
#pragma unroll
    for (int i = 0; i < RPT; ++i) acc[i] = make_float4(0.f, 0.f, 0.f, 0.f);

    for (int k0 = 0; k0 < IN_CH; k0 += 16) {
        {
            int r  = t >> 2;
            int cc = (t & 3) * 4;
            int gr = row0 + r;
            float4 v = make_float4(0.f, 0.f, 0.f, 0.f);
            if (gr < N) v = *(const float4*)(A + (size_t)gr * IN_CH + k0 + cc);
            *(float4*)(&As[r][cc]) = v;
        }
        {
            constexpr int TOT = 16 * KOUT / 4;
            for (int idx = t; idx < TOT; idx += 256) {
                int rr = idx / (KOUT / 4);
                int cc = (idx % (KOUT / 4)) * 4;
                *(float4*)(&Ws[rr][cc]) = *(const float4*)(W + (size_t)(k0 + rr) * KOUT + cc);
            }
        }
        __syncthreads();
#pragma unroll
        for (int kk = 0; kk < 16; ++kk) {
            float4 w = *(const float4*)(&Ws[kk][tx * 4]);
#pragma unroll
            for (int i = 0; i < RPT; ++i) {
                float a = As[ty * RPT + i][kk];
                acc[i].x += a * w.x; acc[i].y += a * w.y;
                acc[i].z += a * w.z; acc[i].w += a * w.w;
            }
        }
        __syncthreads();
    }

    float4 s4 = *(const float4*)(att_s + tx * 4);
    float4 d4 = *(const float4*)(att_d + tx * 4);
#pragma unroll
    for (int i = 0; i < RPT; ++i) {
        int gr = row0 + ty * RPT + i;
        float as = acc[i].x * s4.x + acc[i].y * s4.y + acc[i].z * s4.z + acc[i].w * s4.w;
        float ad = acc[i].x * d4.x + acc[i].y * d4.y + acc[i].z * d4.z + acc[i].w * d4.w;
#pragma unroll
        for (int o = 1; o < RW; o <<= 1) {
            as += __shfl_xor(as, o);
            ad += __shfl_xor(ad, o);
        }
        if (gr < N) {
            ushort4 pk;
            pk.x = f2bf(acc[i].x); pk.y = f2bf(acc[i].y);
            pk.z = f2bf(acc[i].z); pk.w = f2bf(acc[i].w);
            *(ushort4*)(Cbf + (size_t)gr * KOUT + tx * 4) = pk;
            if ((tx % RW) == 0) {
                int h = tx / RW;
                as_[(size_t)gr * HEADS + h] = as;
                ad_[(size_t)gr * HEADS + h] = ad;
            }
        }
    }
}

// ---------------- layer 1 aggregation: block per bucket, LDS accumulators ----------------
// 512 thr = 8 waves sweep the bucket's edges in 8-edge batches.
// Producer: lane computes p for (edge=lane>>3, head=lane&7) -> 1 exp per (e,h).
// Consumer: lane owns channels (lane, lane+64); p via __shfl; acc via ds_add_f32.

__global__ __launch_bounds__(512) void k_agg1_lds(const ushortT* __restrict__ h1bf,
                                                  const float* __restrict__ as1,
                                                  const float* __restrict__ ad1,
                                                  const unsigned* __restrict__ pair,
                                                  const int* __restrict__ bBase,
                                                  const float* __restrict__ b1,
                                                  int N, float* __restrict__ h2in) {
    __shared__ float acc[BKT_NODES * IN_CH];   // 64 KB
    __shared__ float den[BKT_NODES * H1N];     // 4 KB
    __shared__ float ad1s[BKT_NODES * H1N];    // 4 KB
    int b = blockIdx.x, t = threadIdx.x;
    int node0 = b << BKT_SHIFT;
    for (int i = t; i < BKT_NODES * IN_CH; i += 512) acc[i] = 0.f;
    for (int i = t; i < BKT_NODES * H1N; i += 512) {
        den[i] = 0.f;
        int g = node0 + (i >> 3);
        ad1s[i] = (g < N) ? ad1[(size_t)g * H1N + (i & 7)] : 0.f;
    }
    __syncthreads();
    int base = bBase[b];
    int cnt  = bBase[b + 1] - base;
    const unsigned* pp = pair + base;
    int lane = t & 63;
    int wv   = t >> 6;
    int hp   = lane & 7;     // producer head
    int ep   = lane >> 3;    // producer edge within batch
    int h0   = lane >> 4;    // head of channel `lane` (0..3); channel lane+64 -> head 4+h0

    for (int j = wv * 8; j < cnt; j += 64) {
        int idx = j + ep;
        unsigned pk = (idx < cnt) ? pp[idx] : 0u;
        int dl = pk >> 16;
        int s  = pk & 0xFFFFu;
        float p = 0.f;
        if (idx < cnt) {
            p = __expf(leaky(as1[s * H1N + hp] + ad1s[dl * H1N + hp]));
            atomicAdd(&den[dl * H1N + hp], p);
        }
#pragma unroll
        for (int e = 0; e < 8; ++e) {
            if (j + e >= cnt) break;                 // wave-uniform
            unsigned pke = pp[j + e];                // wave-uniform -> scalar load
            int de = pke >> 16;
            int se = pke & 0xFFFFu;
            float pe0 = __shfl(p, e * 8 + h0);
            float pe1 = __shfl(p, e * 8 + 4 + h0);
            float x0 = bf2f(h1bf[(size_t)se * IN_CH + lane]);
            float x1 = bf2f(h1bf[(size_t)se * IN_CH + 64 + lane]);
            atomicAdd(&acc[de * IN_CH + lane], pe0 * x0);
            atomicAdd(&acc[de * IN_CH + 64 + lane], pe1 * x1);
        }
    }
    __syncthreads();
    for (int i = t; i < BKT_NODES * IN_CH; i += 512) {
        int dl = i >> 7, ch = i & 127;
        int g = node0 + dl;
        if (g < N) {
            float o = acc[i] / (den[dl * H1N + (ch >> 4)] + 1e-16f) + b1[ch];
            o = (o > 0.f) ? o : expm1f(o);
            h2in[(size_t)g * IN_CH + ch] = o;
        }
    }
}

// ---------------- layer 2 aggregation + log_softmax: block per bucket ----------------

__global__ __launch_bounds__(512) void k_agg2_lds(const ushortT* __restrict__ h2bf,
                                                  const float* __restrict__ as2,
                                                  const float* __restrict__ ad2,
                                                  const unsigned* __restrict__ pair,
                                                  const int* __restrict__ bBase,
                                                  const float* __restrict__ b2,
                                                  int N, float* __restrict__ out) {
    __shared__ float acc[BKT_NODES * C2N];    // 32 KB
    __shared__ float den[BKT_NODES];
    __shared__ float ad2s[BKT_NODES];
    int b = blockIdx.x, t = threadIdx.x;
    int node0 = b << BKT_SHIFT;
    for (int i = t; i < BKT_NODES * C2N; i += 512) acc[i] = 0.f;
    if (t < BKT_NODES) {
        den[t] = 0.f;
        int g = node0 + t;
        ad2s[t] = (g < N) ? ad2[g] : 0.f;
    }
    __syncthreads();
    int base = bBase[b];
    int cnt  = bBase[b + 1] - base;
    const unsigned* pp = pair + base;
    int lane = t & 63;
    int wv   = t >> 6;
    int ep   = lane >> 3;

    for (int j = wv * 8; j < cnt; j += 64) {
        int idx = j + ep;
        unsigned pk = (idx < cnt) ? pp[idx] : 0u;
        int dl = pk >> 16;
        int s  = pk & 0xFFFFu;
        float p = 0.f;
        if (idx < cnt) {
            p = __expf(leaky(as2[s] + ad2s[dl]));
            if ((lane & 7) == 0) atomicAdd(&den[dl], p);
        }
#pragma unroll
        for (int e = 0; e < 8; ++e) {
            if (j + e >= cnt) break;
            unsigned pke = pp[j + e];
            int de = pke >> 16;
            int se = pke & 0xFFFFu;
            float pe = __shfl(p, e * 8);
            float x = bf2f(h2bf[(size_t)se * C2N + lane]);
            atomicAdd(&acc[de * C2N + lane], pe * x);
        }
    }
    __syncthreads();
    // log_softmax epilogue: wave wv handles nodes wv, wv+8, ...
    for (int dl = wv; dl < BKT_NODES; dl += 8) {
        int g = node0 + dl;
        if (g >= N) continue;
        float o = acc[dl * C2N + lane] / (den[dl] + 1e-16f) + b2[lane];
        float mx = o;
#pragma unroll
        for (int off = 32; off >= 1; off >>= 1) mx = fmaxf(mx, __shfl_xor(mx, off));
        float ee = __expf(o - mx);
        float se2 = ee;
#pragma unroll
        for (int off = 32; off >= 1; off >>= 1) se2 += __shfl_xor(se2, off);
        out[(size_t)g * C2N + lane] = o - mx - logf(se2);
    }
}

// ---------------- launch ----------------

extern "C" void kernel_launch(void* const* d_in, const int* in_sizes, int n_in,
                              void* d_out, int out_size, void* d_ws, size_t ws_size,
                              hipStream_t stream) {
    const float* x      = (const float*)d_in[0];
    const int*   ei     = (const int*)d_in[1];
    const float* W1     = (const float*)d_in[2];
    const float* att_s1 = (const float*)d_in[3];
    const float* att_d1 = (const float*)d_in[4];
    const float* b1     = (const float*)d_in[5];
    const float* W2     = (const float*)d_in[6];
    const float* att_s2 = (const float*)d_in[7];
    const float* att_d2 = (const float*)d_in[8];
    const float* b2     = (const float*)d_in[9];

    int N = in_sizes[0] / IN_CH;
    int E = in_sizes[1] / 2;
    const int* srcA = ei;
    const int* dstA = ei + E;
    int Etot = E + N;
    int nb = (N + BKT_NODES - 1) >> BKT_SHIFT;   // 391 buckets for N=50000

    char* p = (char*)d_ws;
    auto carve = [&](size_t bytes) {
        void* r = (void*)p;
        p += (bytes + 255) & ~(size_t)255;
        return r;
    };
    ushortT* h1bf = (ushortT*)carve((size_t)N * IN_CH * 2);
    ushortT* h2bf = (ushortT*)carve((size_t)N * C2N * 2);
    float* h2in = (float*)carve((size_t)N * IN_CH * 4);
    float* as1  = (float*)carve((size_t)N * H1N * 4);
    float* ad1  = (float*)carve((size_t)N * H1N * 4);
    float* as2  = (float*)carve((size_t)N * 4);
    float* ad2  = (float*)carve((size_t)N * 4);
    int* cnt         = (int*)carve((size_t)nb * NBLK * 4);
    int* bucketTotal = (int*)carve((size_t)nb * 4);
    int* bBase       = (int*)carve((size_t)(nb + 1) * 4);
    unsigned* pair   = (unsigned*)carve((size_t)Etot * 4);

    // bucket-grouped edge list (deterministic counting sort; no global atomics)
    k_cnt<<<NBLK, 512, 0, stream>>>(srcA, dstA, E, N, cnt);
    k_scanrel<<<nb, NBLK, 0, stream>>>(cnt, bucketTotal);
    k_scanbucket<<<1, 512, 0, stream>>>(bucketTotal, nb, bBase);
    k_bin<<<NBLK, 512, 0, stream>>>(srcA, dstA, E, N, cnt, bBase, pair);

    // layer 1
    k_gemm_att<128, 8><<<(N + 63) / 64, 256, 0, stream>>>(x, W1, att_s1, att_d1,
                                                          N, h1bf, as1, ad1);
    k_agg1_lds<<<nb, 512, 0, stream>>>(h1bf, as1, ad1, pair, bBase, b1, N, h2in);

    // layer 2
    k_gemm_att<64, 1><<<(N + 63) / 64, 256, 0, stream>>>(h2in, W2, att_s2, att_d2,
                                                         N, h2bf, as2, ad2);
    k_agg2_lds<<<nb, 512, 0, stream>>>(h2bf, as2, ad2, pair, bBase, b2, N, (float*)d_out);
}

// Round 9
// 243.696 us; speedup vs baseline: 5.2992x; 5.2992x over previous
//
#include <hip/hip_runtime.h>
#include <math.h>

#define IN_CH 128
#define H1N 8
#define C1N 16
#define C2N 64
#define NEG_SLOPE 0.2f

#define BKT_SHIFT 7                 // 128 nodes per bucket
#define BKT_NODES (1 << BKT_SHIFT)
#define NBLK 128                    // blocks for count/bin passes

typedef unsigned short ushortT;

__device__ __forceinline__ ushortT f2bf(float f) {
    unsigned u = __float_as_uint(f);
    unsigned r = u + 0x7FFFu + ((u >> 16) & 1u);
    return (ushortT)(r >> 16);
}
__device__ __forceinline__ float bf2f(ushortT b) {
    return __uint_as_float(((unsigned)b) << 16);
}
__device__ __forceinline__ float leaky(float x) {
    return (x > 0.f) ? x : NEG_SLOPE * x;
}

// ---------------- CSR build: deterministic counting sort, no global atomics ----------------

__global__ __launch_bounds__(512) void k_cnt(const int* __restrict__ src,
                                             const int* __restrict__ dst,
                                             int E, int N, int* __restrict__ cnt) {
    __shared__ int hist[512];
    int blk = blockIdx.x, t = threadIdx.x;
    int nb = (N + BKT_NODES - 1) >> BKT_SHIFT;
    if (t < nb) hist[t] = 0;
    __syncthreads();
    int Etot = E + N;
    int chunk = (Etot + gridDim.x - 1) / gridDim.x;
    int lo = blk * chunk;
    int hi = lo + chunk; if (hi > Etot) hi = Etot;
    for (int i = lo + t; i < hi; i += 512) {
        int d = (i < E) ? dst[i] : (i - E);
        atomicAdd(&hist[d >> BKT_SHIFT], 1);
    }
    __syncthreads();
    if (t < nb) cnt[t * NBLK + blk] = hist[t];
}

__global__ __launch_bounds__(NBLK) void k_scanrel(int* __restrict__ cnt,
                                                  int* __restrict__ bucketTotal) {
    __shared__ int sh[NBLK];
    int b = blockIdx.x, t = threadIdx.x;
    sh[t] = cnt[b * NBLK + t];
    __syncthreads();
    for (int off = 1; off < NBLK; off <<= 1) {
        int v = (t >= off) ? sh[t - off] : 0;
        __syncthreads();
        sh[t] += v;
        __syncthreads();
    }
    if (t == NBLK - 1) bucketTotal[b] = sh[t];
    cnt[b * NBLK + t] = (t == 0) ? 0 : sh[t - 1];
}

__global__ __launch_bounds__(512) void k_scanbucket(const int* __restrict__ bucketTotal,
                                                    int nb, int* __restrict__ bBase,
                                                    int N, int* __restrict__ offsets) {
    __shared__ int sh[512];
    int t = threadIdx.x;
    sh[t] = (t < nb) ? bucketTotal[t] : 0;
    __syncthreads();
    for (int off = 1; off < 512; off <<= 1) {
        int v = (t >= off) ? sh[t - off] : 0;
        __syncthreads();
        sh[t] += v;
        __syncthreads();
    }
    if (t < nb) bBase[t] = (t == 0) ? 0 : sh[t - 1];
    if (t == 511) { bBase[nb] = sh[511]; offsets[N] = sh[511]; }
}

__global__ __launch_bounds__(512) void k_bin(const int* __restrict__ src,
                                             const int* __restrict__ dst,
                                             int E, int N,
                                             const int* __restrict__ cnt,
                                             const int* __restrict__ bBase,
                                             unsigned* __restrict__ pair) {
    __shared__ int cur[512];
    int blk = blockIdx.x, t = threadIdx.x;
    int nb = (N + BKT_NODES - 1) >> BKT_SHIFT;
    if (t < nb) cur[t] = bBase[t] + cnt[t * NBLK + blk];
    __syncthreads();
    int Etot = E + N;
    int chunk = (Etot + gridDim.x - 1) / gridDim.x;
    int lo = blk * chunk;
    int hi = lo + chunk; if (hi > Etot) hi = Etot;
    for (int i = lo + t; i < hi; i += 512) {
        int s, d;
        if (i < E) { s = src[i]; d = dst[i]; }
        else       { s = d = i - E; }
        int b = d >> BKT_SHIFT;
        int pos = atomicAdd(&cur[b], 1);
        pair[pos] = ((unsigned)(d & (BKT_NODES - 1)) << 16) | (unsigned)s;
    }
}

__global__ __launch_bounds__(256) void k_csr_local(const unsigned* __restrict__ pair,
                                                   const int* __restrict__ bBase,
                                                   int N, int* __restrict__ offsets,
                                                   ushortT* __restrict__ csr) {
    __shared__ int hist[BKT_NODES];
    __shared__ int loff[BKT_NODES];
    int b = blockIdx.x;
    int t = threadIdx.x;
    int base = bBase[b];
    int cnt = bBase[b + 1] - base;
    const unsigned* pp = pair + base;

    if (t < BKT_NODES) hist[t] = 0;
    __syncthreads();
    for (int i = t; i < cnt; i += 256) atomicAdd(&hist[pp[i] >> 16], 1);
    __syncthreads();
    if (t < BKT_NODES) loff[t] = hist[t];
    __syncthreads();
    for (int off = 1; off < BKT_NODES; off <<= 1) {
        int v = 0;
        if (t < BKT_NODES && t >= off) v = loff[t - off];
        __syncthreads();
        if (t < BKT_NODES) loff[t] += v;
        __syncthreads();
    }
    int node0 = b << BKT_SHIFT;
    if (t < BKT_NODES) {
        int excl = (t == 0) ? 0 : loff[t - 1];
        hist[t] = excl;
        int g = node0 + t;
        if (g < N) offsets[g] = base + excl;
    }
    __syncthreads();
    for (int i = t; i < cnt; i += 256) {
        unsigned pk = pp[i];
        int pos = atomicAdd(&hist[pk >> 16], 1);
        csr[base + pos] = (ushortT)(pk & 0xFFFFu);
    }
}

// ---------------- GEMM + fused attention coefficients ----------------

template <int KOUT, int HEADS>
__global__ __launch_bounds__(256) void k_gemm_att(const float* __restrict__ A,
                                                  const float* __restrict__ W,
                                                  const float* __restrict__ att_s,
                                                  const float* __restrict__ att_d,
                                                  int N, ushortT* __restrict__ Cbf,
                                                  float* __restrict__ as_,
                                                  float* __restrict__ ad_) {
    constexpr int CG  = KOUT / 4;
    constexpr int TY  = 256 / CG;
    constexpr int RPT = 64 / TY;
    constexpr int RW  = (KOUT / HEADS) / 4;
    static_assert(RW == 4 || RW == 16, "reduce width");
    __shared__ float As[64][16];
    __shared__ float Ws[16][KOUT];
    int t = threadIdx.x;
    int row0 = blockIdx.x * 64;
    int tx = t % CG, ty = t / CG;

    float4 acc[RPT];
#pragma unroll
    for (int i = 0; i < RPT; ++i) acc[i] = make_float4(0.f, 0.f, 0.f, 0.f);

    for (int k0 = 0; k0 < IN_CH; k0 += 16) {
        {
            int r  = t >> 2;
            int cc = (t & 3) * 4;
            int gr = row0 + r;
            float4 v = make_float4(0.f, 0.f, 0.f, 0.f);
            if (gr < N) v = *(const float4*)(A + (size_t)gr * IN_CH + k0 + cc);
            *(float4*)(&As[r][cc]) = v;
        }
        {
            constexpr int TOT = 16 * KOUT / 4;
            for (int idx = t; idx < TOT; idx += 256) {
                int rr = idx / (KOUT / 4);
                int cc = (idx % (KOUT / 4)) * 4;
                *(float4*)(&Ws[rr][cc]) = *(const float4*)(W + (size_t)(k0 + rr) * KOUT + cc);
            }
        }
        __syncthreads();
#pragma unroll
        for (int kk = 0; kk < 16; ++kk) {
            float4 w = *(const float4*)(&Ws[kk][tx * 4]);
#pragma unroll
            for (int i = 0; i < RPT; ++i) {
                float a = As[ty * RPT + i][kk];
                acc[i].x += a * w.x; acc[i].y += a * w.y;
                acc[i].z += a * w.z; acc[i].w += a * w.w;
            }
        }
        __syncthreads();
    }

    float4 s4 = *(const float4*)(att_s + tx * 4);
    float4 d4 = *(const float4*)(att_d + tx * 4);
#pragma unroll
    for (int i = 0; i < RPT; ++i) {
        int gr = row0 + ty * RPT + i;
        float as = acc[i].x * s4.x + acc[i].y * s4.y + acc[i].z * s4.z + acc[i].w * s4.w;
        float ad = acc[i].x * d4.x + acc[i].y * d4.y + acc[i].z * d4.z + acc[i].w * d4.w;
#pragma unroll
        for (int o = 1; o < RW; o <<= 1) {
            as += __shfl_xor(as, o);
            ad += __shfl_xor(ad, o);
        }
        if (gr < N) {
            ushort4 pk;
            pk.x = f2bf(acc[i].x); pk.y = f2bf(acc[i].y);
            pk.z = f2bf(acc[i].z); pk.w = f2bf(acc[i].w);
            *(ushort4*)(Cbf + (size_t)gr * KOUT + tx * 4) = pk;
            if ((tx % RW) == 0) {
                int h = tx / RW;
                as_[(size_t)gr * HEADS + h] = as;
                ad_[(size_t)gr * HEADS + h] = ad;
            }
        }
    }
}

// ---------------- layer 1 aggregation (+bias +ELU) ----------------
// 2 waves per node (block 256 = 2 nodes x 2 waves). Each wave takes
// alternating 8-edge batches; register accumulation; one LDS combine.
// Producer: lane computes p for (edge=lane>>3, head=lane&7) -> 1 exp/(e,h).
// Consumer: lane owns channels 2*lane,2*lane+1 (head hc=lane>>3).

__global__ __launch_bounds__(256) void k_agg1(const ushortT* __restrict__ h1bf,
                       const float* __restrict__ as1, const float* __restrict__ ad1,
                       const int* __restrict__ offsets, const ushortT* __restrict__ csr,
                       const float* __restrict__ b1,
                       int N, float* __restrict__ h2in) {
    __shared__ float comb[2][192];     // per node: 128 acc + 64 denom
    int t = threadIdx.x;
    int half = t >> 7;                 // node within block
    int wv   = (t >> 6) & 1;           // wave within node
    int lane = t & 63;
    int v = blockIdx.x * 2 + half;
    bool alive = (v < N);

    int hc = lane >> 3;                // consumer head
    int hp = lane & 7;                 // producer head
    int ep = lane >> 3;                // producer edge in batch
    float adp = 0.f;
    int beg = 0, end = 0;
    if (alive) {
        adp = ad1[v * H1N + hp];
        beg = offsets[v];
        end = offsets[v + 1];
    }
    float denom = 0.f, acc0 = 0.f, acc1 = 0.f;
    for (int j = beg + wv * 8; j < end; j += 16) {
        int m = end - j; if (m > 8) m = 8;          // wave-uniform
        int sE = 0;
        float p = 0.f;
        if (ep < m) {
            sE = csr[j + ep];
            p = __expf(leaky(as1[sE * H1N + hp] + adp));
        }
        for (int e = 0; e < m; ++e) {
            int srcl = e * 8 + hc;
            float pe = __shfl(p, srcl);
            int   se = __shfl(sE, srcl);
            unsigned q = *(const unsigned*)(h1bf + (size_t)se * IN_CH + lane * 2);
            denom += pe;
            acc0 = fmaf(pe, bf2f((ushortT)(q & 0xFFFFu)), acc0);
            acc1 = fmaf(pe, bf2f((ushortT)(q >> 16)), acc1);
        }
    }
    if (wv == 1) {
        comb[half][lane * 2]     = acc0;
        comb[half][lane * 2 + 1] = acc1;
        comb[half][128 + lane]   = denom;
    }
    __syncthreads();
    if (wv == 0 && alive) {
        acc0  += comb[half][lane * 2];
        acc1  += comb[half][lane * 2 + 1];
        denom += comb[half][128 + lane];
        float inv = 1.f / (denom + 1e-16f);
        float o0 = acc0 * inv + b1[lane * 2];
        float o1 = acc1 * inv + b1[lane * 2 + 1];
        o0 = (o0 > 0.f) ? o0 : expm1f(o0);
        o1 = (o1 > 0.f) ? o1 : expm1f(o1);
        float2 ov; ov.x = o0; ov.y = o1;
        *(float2*)(h2in + (size_t)v * IN_CH + lane * 2) = ov;
    }
}

// ---------------- layer 2 aggregation (+bias) + log_softmax ----------------
// 2 waves per node; lane owns channel lane. Producer: lane&7 computes p for
// edge lane&7 of the batch (1 exp per edge).

__global__ __launch_bounds__(256) void k_agg2(const ushortT* __restrict__ h2bf,
                       const float* __restrict__ as2, const float* __restrict__ ad2,
                       const int* __restrict__ offsets, const ushortT* __restrict__ csr,
                       const float* __restrict__ b2,
                       int N, float* __restrict__ out) {
    __shared__ float comb[2][128];     // per node: 64 acc + 64 denom
    int t = threadIdx.x;
    int half = t >> 7;
    int wv   = (t >> 6) & 1;
    int lane = t & 63;
    int v = blockIdx.x * 2 + half;
    bool alive = (v < N);

    float ad = 0.f;
    int beg = 0, end = 0;
    if (alive) {
        ad = ad2[v];
        beg = offsets[v];
        end = offsets[v + 1];
    }
    float denom = 0.f, acc = 0.f;
    for (int j = beg + wv * 8; j < end; j += 16) {
        int m = end - j; if (m > 8) m = 8;
        int ep = lane & 7;
        int sE = 0;
        float p = 0.f;
        if (ep < m) {
            sE = csr[j + ep];
            p = __expf(leaky(as2[sE] + ad));
        }
        for (int e = 0; e < m; ++e) {
            float pe = __shfl(p, e);
            int   se = __shfl(sE, e);
            float x = bf2f(h2bf[(size_t)se * C2N + lane]);
            denom += pe;
            acc = fmaf(pe, x, acc);
        }
    }
    if (wv == 1) {
        comb[half][lane]      = acc;
        comb[half][64 + lane] = denom;
    }
    __syncthreads();
    if (wv == 0 && alive) {
        acc   += comb[half][lane];
        denom += comb[half][64 + lane];
        float o = acc / (denom + 1e-16f) + b2[lane];
        float mx = o;
#pragma unroll
        for (int off = 32; off >= 1; off >>= 1) mx = fmaxf(mx, __shfl_xor(mx, off));
        float e = __expf(o - mx);
        float se = e;
#pragma unroll
        for (int off = 32; off >= 1; off >>= 1) se += __shfl_xor(se, off);
        out[(size_t)v * C2N + lane] = o - mx - logf(se);
    }
}

// ---------------- launch ----------------

extern "C" void kernel_launch(void* const* d_in, const int* in_sizes, int n_in,
                              void* d_out, int out_size, void* d_ws, size_t ws_size,
                              hipStream_t stream) {
    const float* x      = (const float*)d_in[0];
    const int*   ei     = (const int*)d_in[1];
    const float* W1     = (const float*)d_in[2];
    const float* att_s1 = (const float*)d_in[3];
    const float* att_d1 = (const float*)d_in[4];
    const float* b1     = (const float*)d_in[5];
    const float* W2     = (const float*)d_in[6];
    const float* att_s2 = (const float*)d_in[7];
    const float* att_d2 = (const float*)d_in[8];
    const float* b2     = (const float*)d_in[9];

    int N = in_sizes[0] / IN_CH;
    int E = in_sizes[1] / 2;
    const int* srcA = ei;
    const int* dstA = ei + E;
    int Etot = E + N;
    int nb = (N + BKT_NODES - 1) >> BKT_SHIFT;

    char* p = (char*)d_ws;
    auto carve = [&](size_t bytes) {
        void* r = (void*)p;
        p += (bytes + 255) & ~(size_t)255;
        return r;
    };
    ushortT* h1bf = (ushortT*)carve((size_t)N * IN_CH * 2);
    ushortT* h2bf = (ushortT*)carve((size_t)N * C2N * 2);
    float* h2in = (float*)carve((size_t)N * IN_CH * 4);
    float* as1  = (float*)carve((size_t)N * H1N * 4);
    float* ad1  = (float*)carve((size_t)N * H1N * 4);
    float* as2  = (float*)carve((size_t)N * 4);
    float* ad2  = (float*)carve((size_t)N * 4);
    int* offsets     = (int*)carve((size_t)(N + 1) * 4);
    ushortT* csr     = (ushortT*)carve((size_t)Etot * 2);
    int* cnt         = (int*)carve((size_t)nb * NBLK * 4);
    int* bucketTotal = (int*)carve((size_t)nb * 4);
    int* bBase       = (int*)carve((size_t)(nb + 1) * 4);
    unsigned* pair   = (unsigned*)carve((size_t)Etot * 4);

    // CSR build (deterministic counting sort; no global atomics)
    k_cnt<<<NBLK, 512, 0, stream>>>(srcA, dstA, E, N, cnt);
    k_scanrel<<<nb, NBLK, 0, stream>>>(cnt, bucketTotal);
    k_scanbucket<<<1, 512, 0, stream>>>(bucketTotal, nb, bBase, N, offsets);
    k_bin<<<NBLK, 512, 0, stream>>>(srcA, dstA, E, N, cnt, bBase, pair);
    k_csr_local<<<nb, 256, 0, stream>>>(pair, bBase, N, offsets, csr);

    // layer 1
    k_gemm_att<128, 8><<<(N + 63) / 64, 256, 0, stream>>>(x, W1, att_s1, att_d1,
                                                          N, h1bf, as1, ad1);
    k_agg1<<<(N + 1) / 2, 256, 0, stream>>>(h1bf, as1, ad1, offsets, csr, b1, N, h2in);

    // layer 2
    k_gemm_att<64, 1><<<(N + 63) / 64, 256, 0, stream>>>(h2in, W2, att_s2, att_d2,
                                                         N, h2bf, as2, ad2);
    k_agg2<<<(N + 1) / 2, 256, 0, stream>>>(h2bf, as2, ad2, offsets, csr, b2, N, (float*)d_out);
}

// Round 10
// 189.793 us; speedup vs baseline: 6.8042x; 1.2840x over previous
//
#include <hip/hip_runtime.h>
#include <math.h>

#define IN_CH 128
#define H1N 8
#define C1N 16
#define C2N 64
#define NEG_SLOPE 0.2f

#define BKT_SHIFT 7                 // 128 nodes per bucket
#define BKT_NODES (1 << BKT_SHIFT)
#define NBLK 128                    // blocks for count/bin passes

typedef unsigned short ushortT;

__device__ __forceinline__ ushortT f2bf(float f) {
    unsigned u = __float_as_uint(f);
    unsigned r = u + 0x7FFFu + ((u >> 16) & 1u);
    return (ushortT)(r >> 16);
}
__device__ __forceinline__ float bf2f(ushortT b) {
    return __uint_as_float(((unsigned)b) << 16);
}
__device__ __forceinline__ float leaky(float x) {
    return (x > 0.f) ? x : NEG_SLOPE * x;
}

// ---------------- CSR build: deterministic counting sort, no global atomics ----------------

__global__ __launch_bounds__(512) void k_cnt(const int* __restrict__ src,
                                             const int* __restrict__ dst,
                                             int E, int N, int* __restrict__ cnt) {
    __shared__ int hist[512];
    int blk = blockIdx.x, t = threadIdx.x;
    int nb = (N + BKT_NODES - 1) >> BKT_SHIFT;
    if (t < nb) hist[t] = 0;
    __syncthreads();
    int Etot = E + N;
    int chunk = (Etot + gridDim.x - 1) / gridDim.x;
    int lo = blk * chunk;
    int hi = lo + chunk; if (hi > Etot) hi = Etot;
    for (int i = lo + t; i < hi; i += 512) {
        int d = (i < E) ? dst[i] : (i - E);
        atomicAdd(&hist[d >> BKT_SHIFT], 1);
    }
    __syncthreads();
    if (t < nb) cnt[t * NBLK + blk] = hist[t];
}

__global__ __launch_bounds__(NBLK) void k_scanrel(int* __restrict__ cnt,
                                                  int* __restrict__ bucketTotal) {
    __shared__ int sh[NBLK];
    int b = blockIdx.x, t = threadIdx.x;
    sh[t] = cnt[b * NBLK + t];
    __syncthreads();
    for (int off = 1; off < NBLK; off <<= 1) {
        int v = (t >= off) ? sh[t - off] : 0;
        __syncthreads();
        sh[t] += v;
        __syncthreads();
    }
    if (t == NBLK - 1) bucketTotal[b] = sh[t];
    cnt[b * NBLK + t] = (t == 0) ? 0 : sh[t - 1];
}

__global__ __launch_bounds__(512) void k_scanbucket(const int* __restrict__ bucketTotal,
                                                    int nb, int* __restrict__ bBase,
                                                    int N, int* __restrict__ offsets) {
    __shared__ int sh[512];
    int t = threadIdx.x;
    sh[t] = (t < nb) ? bucketTotal[t] : 0;
    __syncthreads();
    for (int off = 1; off < 512; off <<= 1) {
        int v = (t >= off) ? sh[t - off] : 0;
        __syncthreads();
        sh[t] += v;
        __syncthreads();
    }
    if (t < nb) bBase[t] = (t == 0) ? 0 : sh[t - 1];
    if (t == 511) { bBase[nb] = sh[511]; offsets[N] = sh[511]; }
}

__global__ __launch_bounds__(512) void k_bin(const int* __restrict__ src,
                                             const int* __restrict__ dst,
                                             int E, int N,
                                             const int* __restrict__ cnt,
                                             const int* __restrict__ bBase,
                                             unsigned* __restrict__ pair) {
    __shared__ int cur[512];
    int blk = blockIdx.x, t = threadIdx.x;
    int nb = (N + BKT_NODES - 1) >> BKT_SHIFT;
    if (t < nb) cur[t] = bBase[t] + cnt[t * NBLK + blk];
    __syncthreads();
    int Etot = E + N;
    int chunk = (Etot + gridDim.x - 1) / gridDim.x;
    int lo = blk * chunk;
    int hi = lo + chunk; if (hi > Etot) hi = Etot;
    for (int i = lo + t; i < hi; i += 512) {
        int s, d;
        if (i < E) { s = src[i]; d = dst[i]; }
        else       { s = d = i - E; }
        int b = d >> BKT_SHIFT;
        int pos = atomicAdd(&cur[b], 1);
        pair[pos] = ((unsigned)(d & (BKT_NODES - 1)) << 16) | (unsigned)s;
    }
}

__global__ __launch_bounds__(256) void k_csr_local(const unsigned* __restrict__ pair,
                                                   const int* __restrict__ bBase,
                                                   int N, int* __restrict__ offsets,
                                                   ushortT* __restrict__ csr) {
    __shared__ int hist[BKT_NODES];
    __shared__ int loff[BKT_NODES];
    int b = blockIdx.x;
    int t = threadIdx.x;
    int base = bBase[b];
    int cnt = bBase[b + 1] - base;
    const unsigned* pp = pair + base;

    if (t < BKT_NODES) hist[t] = 0;
    __syncthreads();
    for (int i = t; i < cnt; i += 256) atomicAdd(&hist[pp[i] >> 16], 1);
    __syncthreads();
    if (t < BKT_NODES) loff[t] = hist[t];
    __syncthreads();
    for (int off = 1; off < BKT_NODES; off <<= 1) {
        int v = 0;
        if (t < BKT_NODES && t >= off) v = loff[t - off];
        __syncthreads();
        if (t < BKT_NODES) loff[t] += v;
        __syncthreads();
    }
    int node0 = b << BKT_SHIFT;
    if (t < BKT_NODES) {
        int excl = (t == 0) ? 0 : loff[t - 1];
        hist[t] = excl;
        int g = node0 + t;
        if (g < N) offsets[g] = base + excl;
    }
    __syncthreads();
    for (int i = t; i < cnt; i += 256) {
        unsigned pk = pp[i];
        int pos = atomicAdd(&hist[pk >> 16], 1);
        csr[base + pos] = (ushortT)(pk & 0xFFFFu);
    }
}

// ---------------- GEMM + fused attention coefficients ----------------

template <int KOUT, int HEADS>
__global__ __launch_bounds__(256) void k_gemm_att(const float* __restrict__ A,
                                                  const float* __restrict__ W,
                                                  const float* __restrict__ att_s,
                                                  const float* __restrict__ att_d,
                                                  int N, ushortT* __restrict__ Cbf,
                                                  float* __restrict__ as_,
                                                  float* __restrict__ ad_) {
    constexpr int CG  = KOUT / 4;
    constexpr int TY  = 256 / CG;
    constexpr int RPT = 64 / TY;
    constexpr int RW  = (KOUT / HEADS) / 4;
    static_assert(RW == 4 || RW == 16, "reduce width");
    __shared__ float As[64][16];
    __shared__ float Ws[16][KOUT];
    int t = threadIdx.x;
    int row0 = blockIdx.x * 64;
    int tx = t % CG, ty = t / CG;

    float4 acc[RPT];
#pragma unroll
    for (int i = 0; i < RPT; ++i) acc[i] = make_float4(0.f, 0.f, 0.f, 0.f);

    for (int k0 = 0; k0 < IN_CH; k0 += 16) {
        {
            int r  = t >> 2;
            int cc = (t & 3) * 4;
            int gr = row0 + r;
            float4 v = make_float4(0.f, 0.f, 0.f, 0.f);
            if (gr < N) v = *(const float4*)(A + (size_t)gr * IN_CH + k0 + cc);
            *(float4*)(&As[r][cc]) = v;
        }
        {
            constexpr int TOT = 16 * KOUT / 4;
            for (int idx = t; idx < TOT; idx += 256) {
                int rr = idx / (KOUT / 4);
                int cc = (idx % (KOUT / 4)) * 4;
                *(float4*)(&Ws[rr][cc]) = *(const float4*)(W + (size_t)(k0 + rr) * KOUT + cc);
            }
        }
        __syncthreads();
#pragma unroll
        for (int kk = 0; kk < 16; ++kk) {
            float4 w = *(const float4*)(&Ws[kk][tx * 4]);
#pragma unroll
            for (int i = 0; i < RPT; ++i) {
                float a = As[ty * RPT + i][kk];
                acc[i].x += a * w.x; acc[i].y += a * w.y;
                acc[i].z += a * w.z; acc[i].w += a * w.w;
            }
        }
        __syncthreads();
    }

    float4 s4 = *(const float4*)(att_s + tx * 4);
    float4 d4 = *(const float4*)(att_d + tx * 4);
#pragma unroll
    for (int i = 0; i < RPT; ++i) {
        int gr = row0 + ty * RPT + i;
        float as = acc[i].x * s4.x + acc[i].y * s4.y + acc[i].z * s4.z + acc[i].w * s4.w;
        float ad = acc[i].x * d4.x + acc[i].y * d4.y + acc[i].z * d4.z + acc[i].w * d4.w;
#pragma unroll
        for (int o = 1; o < RW; o <<= 1) {
            as += __shfl_xor(as, o);
            ad += __shfl_xor(ad, o);
        }
        if (gr < N) {
            ushort4 pk;
            pk.x = f2bf(acc[i].x); pk.y = f2bf(acc[i].y);
            pk.z = f2bf(acc[i].z); pk.w = f2bf(acc[i].w);
            *(ushort4*)(Cbf + (size_t)gr * KOUT + tx * 4) = pk;
            if ((tx % RW) == 0) {
                int h = tx / RW;
                as_[(size_t)gr * HEADS + h] = as;
                ad_[(size_t)gr * HEADS + h] = ad;
            }
        }
    }
}

// ---------------- layer 1 aggregation (+bias +ELU) ----------------
// 2 waves per node, interleaved FULL 8-edge batches (compile-time unrolled ->
// 8 concurrent gathers); <8-edge tail handled by exactly one wave.
// Producer: lane computes p for (edge=lane>>3, head=lane&7).
// Consumer: lane owns channels 2*lane,2*lane+1 (head hc=lane>>3).

__global__ __launch_bounds__(256) void k_agg1(const ushortT* __restrict__ h1bf,
                       const float* __restrict__ as1, const float* __restrict__ ad1,
                       const int* __restrict__ offsets, const ushortT* __restrict__ csr,
                       const float* __restrict__ b1,
                       int N, float* __restrict__ h2in) {
    __shared__ float comb[2][192];     // per node: 128 acc + 64 denom
    int t = threadIdx.x;
    int half = t >> 7;                 // node within block
    int wv   = (t >> 6) & 1;           // wave within node
    int lane = t & 63;
    int v = blockIdx.x * 2 + half;
    bool alive = (v < N);

    int hc = lane >> 3;                // consumer head
    int hp = lane & 7;                 // producer head
    int ep = lane >> 3;                // producer edge in batch
    float adp = 0.f;
    int beg = 0, end = 0;
    if (alive) {
        adp = ad1[v * H1N + hp];
        beg = offsets[v];
        end = offsets[v + 1];
    }
    float denom = 0.f, acc0 = 0.f, acc1 = 0.f;
    int j = beg + wv * 8;
    for (; j + 8 <= end; j += 16) {
        int sE = csr[j + ep];
        float p = __expf(leaky(as1[sE * H1N + hp] + adp));
#pragma unroll
        for (int e = 0; e < 8; ++e) {
            int srcl = e * 8 + hc;
            float pe = __shfl(p, srcl);
            int   se = __shfl(sE, srcl);
            unsigned q = *(const unsigned*)(h1bf + (size_t)se * IN_CH + lane * 2);
            denom += pe;
            acc0 = fmaf(pe, bf2f((ushortT)(q & 0xFFFFu)), acc0);
            acc1 = fmaf(pe, bf2f((ushortT)(q >> 16)), acc1);
        }
    }
    if (j < end) {                      // tail (<8 edges), one wave only
        int m = end - j;
        int sE = 0;
        float p = 0.f;
        if (ep < m) {
            sE = csr[j + ep];
            p = __expf(leaky(as1[sE * H1N + hp] + adp));
        }
        for (int e = 0; e < m; ++e) {
            int srcl = e * 8 + hc;
            float pe = __shfl(p, srcl);
            int   se = __shfl(sE, srcl);
            unsigned q = *(const unsigned*)(h1bf + (size_t)se * IN_CH + lane * 2);
            denom += pe;
            acc0 = fmaf(pe, bf2f((ushortT)(q & 0xFFFFu)), acc0);
            acc1 = fmaf(pe, bf2f((ushortT)(q >> 16)), acc1);
        }
    }
    if (wv == 1) {
        comb[half][lane * 2]     = acc0;
        comb[half][lane * 2 + 1] = acc1;
        comb[half][128 + lane]   = denom;
    }
    __syncthreads();
    if (wv == 0 && alive) {
        acc0  += comb[half][lane * 2];
        acc1  += comb[half][lane * 2 + 1];
        denom += comb[half][128 + lane];
        float inv = 1.f / (denom + 1e-16f);
        float o0 = acc0 * inv + b1[lane * 2];
        float o1 = acc1 * inv + b1[lane * 2 + 1];
        o0 = (o0 > 0.f) ? o0 : expm1f(o0);
        o1 = (o1 > 0.f) ? o1 : expm1f(o1);
        float2 ov; ov.x = o0; ov.y = o1;
        *(float2*)(h2in + (size_t)v * IN_CH + lane * 2) = ov;
    }
}

// ---------------- layer 2 aggregation (+bias) + log_softmax ----------------
// 2 waves per node; lane owns channel lane. Producer: lane computes p for
// edge lane&7 of the batch; consumer shfl from lane e.

__global__ __launch_bounds__(256) void k_agg2(const ushortT* __restrict__ h2bf,
                       const float* __restrict__ as2, const float* __restrict__ ad2,
                       const int* __restrict__ offsets, const ushortT* __restrict__ csr,
                       const float* __restrict__ b2,
                       int N, float* __restrict__ out) {
    __shared__ float comb[2][128];     // per node: 64 acc + 64 denom
    int t = threadIdx.x;
    int half = t >> 7;
    int wv   = (t >> 6) & 1;
    int lane = t & 63;
    int v = blockIdx.x * 2 + half;
    bool alive = (v < N);

    float ad = 0.f;
    int beg = 0, end = 0;
    if (alive) {
        ad = ad2[v];
        beg = offsets[v];
        end = offsets[v + 1];
    }
    int ep = lane & 7;
    float denom = 0.f, acc = 0.f;
    int j = beg + wv * 8;
    for (; j + 8 <= end; j += 16) {
        int sE = csr[j + ep];
        float p = __expf(leaky(as2[sE] + ad));
#pragma unroll
        for (int e = 0; e < 8; ++e) {
            float pe = __shfl(p, e);
            int   se = __shfl(sE, e);
            float x = bf2f(h2bf[(size_t)se * C2N + lane]);
            denom += pe;
            acc = fmaf(pe, x, acc);
        }
    }
    if (j < end) {                      // tail, one wave only
        int m = end - j;
        int sE = 0;
        float p = 0.f;
        if (ep < m) {
            sE = csr[j + ep];
            p = __expf(leaky(as2[sE] + ad));
        }
        for (int e = 0; e < m; ++e) {
            float pe = __shfl(p, e);
            int   se = __shfl(sE, e);
            float x = bf2f(h2bf[(size_t)se * C2N + lane]);
            denom += pe;
            acc = fmaf(pe, x, acc);
        }
    }
    if (wv == 1) {
        comb[half][lane]      = acc;
        comb[half][64 + lane] = denom;
    }
    __syncthreads();
    if (wv == 0 && alive) {
        acc   += comb[half][lane];
        denom += comb[half][64 + lane];
        float o = acc / (denom + 1e-16f) + b2[lane];
        float mx = o;
#pragma unroll
        for (int off = 32; off >= 1; off >>= 1) mx = fmaxf(mx, __shfl_xor(mx, off));
        float e = __expf(o - mx);
        float se = e;
#pragma unroll
        for (int off = 32; off >= 1; off >>= 1) se += __shfl_xor(se, off);
        out[(size_t)v * C2N + lane] = o - mx - logf(se);
    }
}

// ---------------- launch ----------------

extern "C" void kernel_launch(void* const* d_in, const int* in_sizes, int n_in,
                              void* d_out, int out_size, void* d_ws, size_t ws_size,
                              hipStream_t stream) {
    const float* x      = (const float*)d_in[0];
    const int*   ei     = (const int*)d_in[1];
    const float* W1     = (const float*)d_in[2];
    const float* att_s1 = (const float*)d_in[3];
    const float* att_d1 = (const float*)d_in[4];
    const float* b1     = (const float*)d_in[5];
    const float* W2     = (const float*)d_in[6];
    const float* att_s2 = (const float*)d_in[7];
    const float* att_d2 = (const float*)d_in[8];
    const float* b2     = (const float*)d_in[9];

    int N = in_sizes[0] / IN_CH;
    int E = in_sizes[1] / 2;
    const int* srcA = ei;
    const int* dstA = ei + E;
    int Etot = E + N;
    int nb = (N + BKT_NODES - 1) >> BKT_SHIFT;

    char* p = (char*)d_ws;
    auto carve = [&](size_t bytes) {
        void* r = (void*)p;
        p += (bytes + 255) & ~(size_t)255;
        return r;
    };
    ushortT* h1bf = (ushortT*)carve((size_t)N * IN_CH * 2);
    ushortT* h2bf = (ushortT*)carve((size_t)N * C2N * 2);
    float* h2in = (float*)carve((size_t)N * IN_CH * 4);
    float* as1  = (float*)carve((size_t)N * H1N * 4);
    float* ad1  = (float*)carve((size_t)N * H1N * 4);
    float* as2  = (float*)carve((size_t)N * 4);
    float* ad2  = (float*)carve((size_t)N * 4);
    int* offsets     = (int*)carve((size_t)(N + 1) * 4);
    ushortT* csr     = (ushortT*)carve((size_t)Etot * 2);
    int* cnt         = (int*)carve((size_t)nb * NBLK * 4);
    int* bucketTotal = (int*)carve((size_t)nb * 4);
    int* bBase       = (int*)carve((size_t)(nb + 1) * 4);
    unsigned* pair   = (unsigned*)carve((size_t)Etot * 4);

    // CSR build (deterministic counting sort; no global atomics)
    k_cnt<<<NBLK, 512, 0, stream>>>(srcA, dstA, E, N, cnt);
    k_scanrel<<<nb, NBLK, 0, stream>>>(cnt, bucketTotal);
    k_scanbucket<<<1, 512, 0, stream>>>(bucketTotal, nb, bBase, N, offsets);
    k_bin<<<NBLK, 512, 0, stream>>>(srcA, dstA, E, N, cnt, bBase, pair);
    k_csr_local<<<nb, 256, 0, stream>>>(pair, bBase, N, offsets, csr);

    // layer 1
    k_gemm_att<128, 8><<<(N + 63) / 64, 256, 0, stream>>>(x, W1, att_s1, att_d1,
                                                          N, h1bf, as1, ad1);
    k_agg1<<<(N + 1) / 2, 256, 0, stream>>>(h1bf, as1, ad1, offsets, csr, b1, N, h2in);

    // layer 2
    k_gemm_att<64, 1><<<(N + 63) / 64, 256, 0, stream>>>(h2in, W2, att_s2, att_d2,
                                                         N, h2bf, as2, ad2);
    k_agg2<<<(N + 1) / 2, 256, 0, stream>>>(h2bf, as2, ad2, offsets, csr, b2, N, (float*)d_out);
}